// Round 6
// baseline (748.444 us; speedup 1.0000x reference)
//
#include <hip/hip_runtime.h>

#define BATCH 8
#define DIM 192
#define HH 128
#define WW 128
#define KS 7
#define PAD 3
#define HID 48
#define KK 49            // KS*KS
#define BN_EPS 1e-5f

#define TILE_H 32
#define SROWS (TILE_H + KS - 1)      // 38
#define NSLOT (SROWS * (WW / 4))     // 1216 float4 slots = 19*64 -> wave-uniform guard ok
#define NTILE (HH / TILE_H)          // 4
#define RPT   4                      // output rows per thread (8 strips x 4 rows)

static_assert(NSLOT % 64 == 0, "staging guard must be wave-uniform");

// ---------------- Kernel A: global average pool over H*W ----------------
__global__ __launch_bounds__(256) void pool_kernel(const float* __restrict__ x,
                                                   float* __restrict__ pooled) {
    const int bc = blockIdx.x;                       // 0..B*DIM-1
    const float4* p = (const float4*)(x + (size_t)bc * HH * WW);
    const int t = threadIdx.x;
    float s = 0.f;
#pragma unroll
    for (int i = 0; i < 16; ++i) {                   // 16384 floats = 4096 float4 / 256 thr
        float4 v = p[t + i * 256];
        s += (v.x + v.y) + (v.z + v.w);
    }
#pragma unroll
    for (int off = 32; off > 0; off >>= 1) s += __shfl_down(s, off, 64);
    __shared__ float wsum[4];
    const int wave = t >> 6, lane = t & 63;
    if (lane == 0) wsum[wave] = s;
    __syncthreads();
    if (t == 0) {
        float tot = (wsum[0] + wsum[1]) + (wsum[2] + wsum[3]);
        pooled[bc] = tot * (1.0f / (HH * WW));
    }
}

// ---------------- Kernel B: fused weight-gen + depthwise 7x7 conv ----------
// ABLATION ROUND (R6): R2's kernel with the SGPR-weight experiment reverted
// to R0's proven form (wreg in VGPRs, launch_bounds(256,4) -> no forced
// spills). TILE_H=32 geometry is now the ONLY delta vs the harness-verified
// R0 kernel. If this passes, geometry is proven and the readfirstlane/
// launch_bounds(256,6) combo was the correctness bug; if this fails at
// ~2e-2, the geometry is the bug and readfirstlane is exonerated.
// Staging: async global_load_lds DMA, 16B/lane. m104/m108 rule: LDS dest =
// wave-uniform base + lane*16; NSLOT = 1216 = 19*64 and each wave spans a
// contiguous 64-slot range, so `s < NSLOT` is wave-uniform -> safe guard.
// Out-of-image (but in-buffer) slots take per-lane-clamped sources and are
// zero-overwritten post-barrier (only tiles 0 and 3 have halo rows).
__global__ __launch_bounds__(256, 4) void dwconv_fused_kernel(
        const float* __restrict__ x,
        const float* __restrict__ pooled,
        const float* __restrict__ w1,
        const float* __restrict__ gamma,
        const float* __restrict__ beta,
        const float* __restrict__ mean,
        const float* __restrict__ var,
        const float* __restrict__ w2,
        const float* __restrict__ b2,
        const float* __restrict__ bias,
        float* __restrict__ out) {
    __shared__ float smem[SROWS][WW];                // 38*128*4 = 19456 B
    __shared__ float y_s[HID];
    __shared__ float wk_s[KK];
    const int tile = blockIdx.x & (NTILE - 1);       // tiles of a channel adjacent
    const int bc = blockIdx.x >> 2;
    const int b = bc / DIM;
    const int c = bc % DIM;
    const int t = threadIdx.x;
    const int r0 = tile * TILE_H;

    // ---- issue async staging DMA first ----
    // valid input rows: [r0-3, r0+34] ∩ [0,128)
    const int slo = (tile == 0) ? PAD * (WW / 4) : 0;                       // 96 or 0
    const int shi = (tile == NTILE - 1) ? (SROWS - PAD) * (WW / 4) : NSLOT; // 1120 or 1216
    const float* xbase = x + (size_t)bc * HH * WW + (ptrdiff_t)(r0 - PAD) * WW;

#pragma unroll
    for (int i = 0; i < (NSLOT + 255) / 256; ++i) {  // 5 iters
        const int s = t + i * 256;
        if (s < NSLOT) {                             // wave-uniform (1216 = 19*64)
            int sc = s;                              // clamp SOURCE only (per-lane ok)
            if (sc < slo) sc = slo;
            if (sc >= shi) sc = shi - 1;
            __builtin_amdgcn_global_load_lds(
                (const __attribute__((address_space(1))) void*)(xbase + (size_t)sc * 4),
                (__attribute__((address_space(3))) void*)((float*)smem + (size_t)s * 4),
                16, 0, 0);
        }
    }

    // ---- inline weight generation, stage 1: y = relu(BN(pooled[b] @ w1^T)) ----
    if (t < HID) {
        const float4* pr = (const float4*)(pooled + b * DIM);
        const float4* wr = (const float4*)(w1 + (size_t)t * DIM);
        float acc = 0.f;
#pragma unroll
        for (int j = 0; j < DIM / 4; ++j) {
            float4 pv = pr[j], wv = wr[j];
            acc += pv.x * wv.x + pv.y * wv.y + pv.z * wv.z + pv.w * wv.w;
        }
        float yv = (acc - mean[t]) * rsqrtf(var[t] + BN_EPS) * gamma[t] + beta[t];
        y_s[t] = yv > 0.f ? yv : 0.f;
    }
    __syncthreads();                                 // y_s visible; DMA drained

    // ---- stage 2: wk[k] = b2 + y . w2row   |   zero-fill 3 halo rows ----
    if (t < KK) {
        const int o = c * KK + t;
        const float4* w2r = (const float4*)(w2 + (size_t)o * HID);
        float acc = b2[o];
#pragma unroll
        for (int j = 0; j < HID / 4; ++j) {
            float4 wv = w2r[j];
            acc += y_s[4 * j] * wv.x + y_s[4 * j + 1] * wv.y +
                   y_s[4 * j + 2] * wv.z + y_s[4 * j + 3] * wv.w;
        }
        wk_s[t] = acc;
    } else if (t >= 160) {                           // 96 threads, 96 float4 slots
        const int zi = t - 160;
        if (tile == 0) {
            ((float4*)smem)[zi] = make_float4(0.f, 0.f, 0.f, 0.f);
        } else if (tile == NTILE - 1) {
            ((float4*)smem)[(SROWS - PAD) * (WW / 4) + zi] =
                make_float4(0.f, 0.f, 0.f, 0.f);
        }
    }
    __syncthreads();

    // ---- weights in VGPRs (R0-proven form) ----
    float wreg[KK];
#pragma unroll
    for (int i = 0; i < KK; ++i) wreg[i] = wk_s[i];
    const float bv = bias[c];

    // ---- compute: 8 strips x 4 rows, sliding window over 10 input rows ----
    const int c4 = t & 31;                           // 4-col group
    const int strip = t >> 5;                        // 0..7
    const int sbase = strip * RPT;
    float* outp = out + (size_t)bc * HH * WW + (size_t)(r0 + sbase) * WW + c4 * 4;

    float acc[RPT][4];
#pragma unroll
    for (int i = 0; i < RPT; ++i)
        acc[i][0] = acc[i][1] = acc[i][2] = acc[i][3] = 0.f;

#pragma unroll
    for (int ir = 0; ir < RPT + KS - 1; ++ir) {      // 10 input rows
        const float4* row4 = (const float4*)&smem[sbase + ir][0];
        const float4 f1 = row4[c4];
        float4 f0 = make_float4(0.f, 0.f, 0.f, 0.f);
        float4 f2 = make_float4(0.f, 0.f, 0.f, 0.f);
        if (c4 > 0)  f0 = row4[c4 - 1];              // cols -4..-1 (zero at left edge)
        if (c4 < 31) f2 = row4[c4 + 1];              // cols +4..+7 (zero at right edge)
        const float v[12] = {f0.x, f0.y, f0.z, f0.w,
                             f1.x, f1.y, f1.z, f1.w,
                             f2.x, f2.y, f2.z, f2.w};
#pragma unroll
        for (int ky = 0; ky < KS; ++ky) {
            const int o = ir - ky;                   // pending output row (compile-time)
            if (o >= 0 && o < RPT) {
                float* a = acc[o];
#pragma unroll
                for (int kx = 0; kx < KS; ++kx) {
                    const float wv = wreg[ky * KS + kx];
                    a[0] += wv * v[1 + kx];
                    a[1] += wv * v[2 + kx];
                    a[2] += wv * v[3 + kx];
                    a[3] += wv * v[4 + kx];
                }
            }
        }
        if (ir >= KS - 1) {                          // output row ir-6 complete
            float* a = acc[ir - (KS - 1)];
            float4 o4 = make_float4(a[0] + bv, a[1] + bv, a[2] + bv, a[3] + bv);
            *((float4*)(outp + (size_t)(ir - (KS - 1)) * WW)) = o4;
        }
    }
}

extern "C" void kernel_launch(void* const* d_in, const int* in_sizes, int n_in,
                              void* d_out, int out_size, void* d_ws, size_t ws_size,
                              hipStream_t stream) {
    const float* x     = (const float*)d_in[0];
    const float* w1    = (const float*)d_in[1];
    const float* gamma = (const float*)d_in[2];
    const float* beta  = (const float*)d_in[3];
    const float* mean  = (const float*)d_in[4];
    const float* var   = (const float*)d_in[5];
    const float* w2    = (const float*)d_in[6];
    const float* b2    = (const float*)d_in[7];
    const float* bias  = (const float*)d_in[8];
    float* out = (float*)d_out;

    float* pooled = (float*)d_ws;                    // B*DIM floats (6 KB, proven size)

    pool_kernel<<<BATCH * DIM, 256, 0, stream>>>(x, pooled);
    dwconv_fused_kernel<<<BATCH * DIM * NTILE, 256, 0, stream>>>(
        x, pooled, w1, gamma, beta, mean, var, w2, b2, bias, out);
}

// Round 8
// 258.147 us; speedup vs baseline: 2.8993x; 2.8993x over previous
//
#include <hip/hip_runtime.h>

#define BATCH 8
#define DIM 192
#define HH 128
#define WW 128
#define KS 7
#define PAD 3
#define HID 48
#define KK 49            // KS*KS
#define BN_EPS 1e-5f

#define TILE_H 32
#define SROWS (TILE_H + KS - 1)      // 38
#define NSLOT (SROWS * (WW / 4))     // 1216 float4 slots = 19*64 -> wave-uniform guard ok
#define NTILE (HH / TILE_H)          // 4
#define RPT   4                      // output rows per thread (8 strips x 4 rows)

static_assert(NSLOT % 64 == 0, "staging guard must be wave-uniform");

// ---------------- Kernel A: global average pool over H*W ----------------
__global__ __launch_bounds__(256) void pool_kernel(const float* __restrict__ x,
                                                   float* __restrict__ pooled) {
    const int bc = blockIdx.x;                       // 0..B*DIM-1
    const float4* p = (const float4*)(x + (size_t)bc * HH * WW);
    const int t = threadIdx.x;
    float s = 0.f;
#pragma unroll
    for (int i = 0; i < 16; ++i) {                   // 16384 floats = 4096 float4 / 256 thr
        float4 v = p[t + i * 256];
        s += (v.x + v.y) + (v.z + v.w);
    }
#pragma unroll
    for (int off = 32; off > 0; off >>= 1) s += __shfl_down(s, off, 64);
    __shared__ float wsum[4];
    const int wave = t >> 6, lane = t & 63;
    if (lane == 0) wsum[wave] = s;
    __syncthreads();
    if (t == 0) {
        float tot = (wsum[0] + wsum[1]) + (wsum[2] + wsum[3]);
        pooled[bc] = tot * (1.0f / (HH * WW));
    }
}

// ---------------- Kernel B: fused weight-gen + depthwise 7x7 conv ----------
// R7/R8: single change vs the PASSING R6 kernel: __launch_bounds__(256,4) ->
// __launch_bounds__(256). Evidence: the 2nd launch-bounds arg pinned VGPRs
// to 64 (R6 counters) while the compute loop needs ~90 live -> total scratch
// spill (FETCH 1.3 GB, dur 586 us). R0's fast+correct config used plain
// (256) -> VGPR 128, no spills. TILE_H=32 / RPT=4 geometry is R6-proven.
// SGPR-weight experiment (readfirstlane) is abandoned: 2 correctness
// failures (R1/R2) traced to it + tight bounds.
// Staging: async global_load_lds DMA, 16B/lane. m104/m108 rule: LDS dest =
// wave-uniform base + lane*16; NSLOT = 1216 = 19*64 and each wave spans a
// contiguous 64-slot range, so `s < NSLOT` is wave-uniform -> safe guard.
// Out-of-image (but in-buffer) slots take per-lane-clamped sources and are
// zero-overwritten post-barrier (only tiles 0 and 3 have halo rows).
__global__ __launch_bounds__(256) void dwconv_fused_kernel(
        const float* __restrict__ x,
        const float* __restrict__ pooled,
        const float* __restrict__ w1,
        const float* __restrict__ gamma,
        const float* __restrict__ beta,
        const float* __restrict__ mean,
        const float* __restrict__ var,
        const float* __restrict__ w2,
        const float* __restrict__ b2,
        const float* __restrict__ bias,
        float* __restrict__ out) {
    __shared__ float smem[SROWS][WW];                // 38*128*4 = 19456 B
    __shared__ float y_s[HID];
    __shared__ float wk_s[KK];
    const int tile = blockIdx.x & (NTILE - 1);       // tiles of a channel adjacent
    const int bc = blockIdx.x >> 2;
    const int b = bc / DIM;
    const int c = bc % DIM;
    const int t = threadIdx.x;
    const int r0 = tile * TILE_H;

    // ---- issue async staging DMA first ----
    // valid input rows: [r0-3, r0+34] ∩ [0,128)
    const int slo = (tile == 0) ? PAD * (WW / 4) : 0;                       // 96 or 0
    const int shi = (tile == NTILE - 1) ? (SROWS - PAD) * (WW / 4) : NSLOT; // 1120 or 1216
    const float* xbase = x + (size_t)bc * HH * WW + (ptrdiff_t)(r0 - PAD) * WW;

#pragma unroll
    for (int i = 0; i < (NSLOT + 255) / 256; ++i) {  // 5 iters
        const int s = t + i * 256;
        if (s < NSLOT) {                             // wave-uniform (1216 = 19*64)
            int sc = s;                              // clamp SOURCE only (per-lane ok)
            if (sc < slo) sc = slo;
            if (sc >= shi) sc = shi - 1;
            __builtin_amdgcn_global_load_lds(
                (const __attribute__((address_space(1))) void*)(xbase + (size_t)sc * 4),
                (__attribute__((address_space(3))) void*)((float*)smem + (size_t)s * 4),
                16, 0, 0);
        }
    }

    // ---- inline weight generation, stage 1: y = relu(BN(pooled[b] @ w1^T)) ----
    if (t < HID) {
        const float4* pr = (const float4*)(pooled + b * DIM);
        const float4* wr = (const float4*)(w1 + (size_t)t * DIM);
        float acc = 0.f;
#pragma unroll
        for (int j = 0; j < DIM / 4; ++j) {
            float4 pv = pr[j], wv = wr[j];
            acc += pv.x * wv.x + pv.y * wv.y + pv.z * wv.z + pv.w * wv.w;
        }
        float yv = (acc - mean[t]) * rsqrtf(var[t] + BN_EPS) * gamma[t] + beta[t];
        y_s[t] = yv > 0.f ? yv : 0.f;
    }
    __syncthreads();                                 // y_s visible; DMA drained

    // ---- stage 2: wk[k] = b2 + y . w2row   |   zero-fill 3 halo rows ----
    if (t < KK) {
        const int o = c * KK + t;
        const float4* w2r = (const float4*)(w2 + (size_t)o * HID);
        float acc = b2[o];
#pragma unroll
        for (int j = 0; j < HID / 4; ++j) {
            float4 wv = w2r[j];
            acc += y_s[4 * j] * wv.x + y_s[4 * j + 1] * wv.y +
                   y_s[4 * j + 2] * wv.z + y_s[4 * j + 3] * wv.w;
        }
        wk_s[t] = acc;
    } else if (t >= 160) {                           // 96 threads, 96 float4 slots
        const int zi = t - 160;
        if (tile == 0) {
            ((float4*)smem)[zi] = make_float4(0.f, 0.f, 0.f, 0.f);
        } else if (tile == NTILE - 1) {
            ((float4*)smem)[(SROWS - PAD) * (WW / 4) + zi] =
                make_float4(0.f, 0.f, 0.f, 0.f);
        }
    }
    __syncthreads();

    // ---- weights in VGPRs (R0-proven form) ----
    float wreg[KK];
#pragma unroll
    for (int i = 0; i < KK; ++i) wreg[i] = wk_s[i];
    const float bv = bias[c];

    // ---- compute: 8 strips x 4 rows, sliding window over 10 input rows ----
    const int c4 = t & 31;                           // 4-col group
    const int strip = t >> 5;                        // 0..7
    const int sbase = strip * RPT;
    float* outp = out + (size_t)bc * HH * WW + (size_t)(r0 + sbase) * WW + c4 * 4;

    float acc[RPT][4];
#pragma unroll
    for (int i = 0; i < RPT; ++i)
        acc[i][0] = acc[i][1] = acc[i][2] = acc[i][3] = 0.f;

#pragma unroll
    for (int ir = 0; ir < RPT + KS - 1; ++ir) {      // 10 input rows
        const float4* row4 = (const float4*)&smem[sbase + ir][0];
        const float4 f1 = row4[c4];
        float4 f0 = make_float4(0.f, 0.f, 0.f, 0.f);
        float4 f2 = make_float4(0.f, 0.f, 0.f, 0.f);
        if (c4 > 0)  f0 = row4[c4 - 1];              // cols -4..-1 (zero at left edge)
        if (c4 < 31) f2 = row4[c4 + 1];              // cols +4..+7 (zero at right edge)
        const float v[12] = {f0.x, f0.y, f0.z, f0.w,
                             f1.x, f1.y, f1.z, f1.w,
                             f2.x, f2.y, f2.z, f2.w};
#pragma unroll
        for (int ky = 0; ky < KS; ++ky) {
            const int o = ir - ky;                   // pending output row (compile-time)
            if (o >= 0 && o < RPT) {
                float* a = acc[o];
#pragma unroll
                for (int kx = 0; kx < KS; ++kx) {
                    const float wv = wreg[ky * KS + kx];
                    a[0] += wv * v[1 + kx];
                    a[1] += wv * v[2 + kx];
                    a[2] += wv * v[3 + kx];
                    a[3] += wv * v[4 + kx];
                }
            }
        }
        if (ir >= KS - 1) {                          // output row ir-6 complete
            float* a = acc[ir - (KS - 1)];
            float4 o4 = make_float4(a[0] + bv, a[1] + bv, a[2] + bv, a[3] + bv);
            *((float4*)(outp + (size_t)(ir - (KS - 1)) * WW)) = o4;
        }
    }
}

extern "C" void kernel_launch(void* const* d_in, const int* in_sizes, int n_in,
                              void* d_out, int out_size, void* d_ws, size_t ws_size,
                              hipStream_t stream) {
    const float* x     = (const float*)d_in[0];
    const float* w1    = (const float*)d_in[1];
    const float* gamma = (const float*)d_in[2];
    const float* beta  = (const float*)d_in[3];
    const float* mean  = (const float*)d_in[4];
    const float* var   = (const float*)d_in[5];
    const float* w2    = (const float*)d_in[6];
    const float* b2    = (const float*)d_in[7];
    const float* bias  = (const float*)d_in[8];
    float* out = (float*)d_out;

    float* pooled = (float*)d_ws;                    // B*DIM floats (6 KB, proven size)

    pool_kernel<<<BATCH * DIM, 256, 0, stream>>>(x, pooled);
    dwconv_fused_kernel<<<BATCH * DIM * NTILE, 256, 0, stream>>>(
        x, pooled, w1, gamma, beta, mean, var, w2, b2, bias, out);
}

// Round 9
// 257.636 us; speedup vs baseline: 2.9050x; 1.0020x over previous
//
#include <hip/hip_runtime.h>

#define BATCH 8
#define DIM 192
#define HH 128
#define WW 128
#define KS 7
#define PAD 3
#define HID 48
#define KK 49            // KS*KS
#define BN_EPS 1e-5f

#define TILE_H 32
#define SROWS (TILE_H + KS - 1)      // 38
#define NSLOT (SROWS * (WW / 4))     // 1216 float4 slots = 19*64 -> wave-uniform guard ok
#define NTILE (HH / TILE_H)          // 4
#define RPT   4                      // output rows per thread (8 strips x 4 rows)

static_assert(NSLOT % 64 == 0, "staging guard must be wave-uniform");

// ---------------- Kernel A: global average pool over H*W ----------------
__global__ __launch_bounds__(256) void pool_kernel(const float* __restrict__ x,
                                                   float* __restrict__ pooled) {
    const int bc = blockIdx.x;                       // 0..B*DIM-1
    const float4* p = (const float4*)(x + (size_t)bc * HH * WW);
    const int t = threadIdx.x;
    float s = 0.f;
#pragma unroll
    for (int i = 0; i < 16; ++i) {                   // 16384 floats = 4096 float4 / 256 thr
        float4 v = p[t + i * 256];
        s += (v.x + v.y) + (v.z + v.w);
    }
#pragma unroll
    for (int off = 32; off > 0; off >>= 1) s += __shfl_down(s, off, 64);
    __shared__ float wsum[4];
    const int wave = t >> 6, lane = t & 63;
    if (lane == 0) wsum[wave] = s;
    __syncthreads();
    if (t == 0) {
        float tot = (wsum[0] + wsum[1]) + (wsum[2] + wsum[3]);
        pooled[bc] = tot * (1.0f / (HH * WW));
    }
}

// ---------------- Kernel B: fused weight-gen + depthwise 7x7 conv ----------
// R9: one block per (b,c) channel (grid 1536, was 6144). wgen runs ONCE per
// channel (was 4x redundant), then 4 row-tiles stream through a double-
// buffered LDS: tile k+1's global_load_lds DMA is issued at the top of tile
// k's compute, so HBM latency hides under ~2.6us of FMA. Plain
// __syncthreads() at loop bottom is the drain (per-wave vmcnt(0)) -- no
// counted-vmcnt, same sync primitive R0/R8 verified. Buffer k^1 is written
// only after the barrier proving all waves finished reading it.
// Occupancy: VGPR 128 binds at 16 waves/CU (m69 halving points) -- LDS
// 2x19456+wk/y ~= 39.9KB also 4 blocks/CU, so dbuf costs no residency.
// Evidence trail: R6 proved TILE_H=32/RPT=4 math (absmax 9.8e-4); R8 proved
// natural VGPR allocation (128, no spills). 2nd launch_bounds arg is POISON
// on this toolchain (R2 correctness, R6 64-VGPR spill disaster): never used.
// Staging: async global_load_lds DMA, 16B/lane, wave-uniform LDS dest
// (m104/m108); out-of-image slots take clamped sources, zero-overwritten
// post-drain (tile0 top 3 rows in wgen phase2; tile3 bottom 3 rows before
// its compute).
__global__ __launch_bounds__(256) void dwconv_fused_kernel(
        const float* __restrict__ x,
        const float* __restrict__ pooled,
        const float* __restrict__ w1,
        const float* __restrict__ gamma,
        const float* __restrict__ beta,
        const float* __restrict__ mean,
        const float* __restrict__ var,
        const float* __restrict__ w2,
        const float* __restrict__ b2,
        const float* __restrict__ bias,
        float* __restrict__ out) {
    __shared__ float smem[2][SROWS][WW];             // 2*38*128*4 = 38912 B
    __shared__ float y_s[HID];
    __shared__ float wk_s[KK];
    const int bc = blockIdx.x;                       // 0..1535
    const int b = bc / DIM;
    const int c = bc % DIM;
    const int t = threadIdx.x;
    const float* xchan = x + (size_t)bc * HH * WW;

    // stage(tile, bufi): issue async DMA of tile's 38 rows into smem[bufi].
    // Identical clamp math to the R8-verified kernel, tile-parameterized.
    auto stage = [&](int tile, int bufi) {
        const int slo = (tile == 0) ? PAD * (WW / 4) : 0;                       // 96 or 0
        const int shi = (tile == NTILE - 1) ? (SROWS - PAD) * (WW / 4) : NSLOT; // 1120 or 1216
        const float* xbase = xchan + (ptrdiff_t)(tile * TILE_H - PAD) * WW;
        float* dst = &smem[bufi][0][0];
#pragma unroll
        for (int i = 0; i < (NSLOT + 255) / 256; ++i) {  // 5 iters
            const int s = t + i * 256;
            if (s < NSLOT) {                             // wave-uniform (1216 = 19*64)
                int sc = s;                              // clamp SOURCE only (per-lane ok)
                if (sc < slo) sc = slo;
                if (sc >= shi) sc = shi - 1;
                __builtin_amdgcn_global_load_lds(
                    (const __attribute__((address_space(1))) void*)(xbase + (size_t)sc * 4),
                    (__attribute__((address_space(3))) void*)(dst + (size_t)s * 4),
                    16, 0, 0);
            }
        }
    };

    stage(0, 0);                                     // tile0 DMA overlaps wgen

    // ---- inline weight generation, stage 1: y = relu(BN(pooled[b] @ w1^T)) ----
    if (t < HID) {
        const float4* pr = (const float4*)(pooled + b * DIM);
        const float4* wr = (const float4*)(w1 + (size_t)t * DIM);
        float acc = 0.f;
#pragma unroll
        for (int j = 0; j < DIM / 4; ++j) {
            float4 pv = pr[j], wv = wr[j];
            acc += pv.x * wv.x + pv.y * wv.y + pv.z * wv.z + pv.w * wv.w;
        }
        float yv = (acc - mean[t]) * rsqrtf(var[t] + BN_EPS) * gamma[t] + beta[t];
        y_s[t] = yv > 0.f ? yv : 0.f;
    }
    __syncthreads();                                 // y_s visible; tile0 DMA drained

    // ---- stage 2: wk[k] = b2 + y . w2row   |   zero-fill tile0 top halo ----
    if (t < KK) {
        const int o = c * KK + t;
        const float4* w2r = (const float4*)(w2 + (size_t)o * HID);
        float acc = b2[o];
#pragma unroll
        for (int j = 0; j < HID / 4; ++j) {
            float4 wv = w2r[j];
            acc += y_s[4 * j] * wv.x + y_s[4 * j + 1] * wv.y +
                   y_s[4 * j + 2] * wv.z + y_s[4 * j + 3] * wv.w;
        }
        wk_s[t] = acc;
    } else if (t >= 160) {                           // 96 threads, 96 float4 slots
        const int zi = t - 160;                      // rows -3..-1 of tile0 (buf0)
        ((float4*)&smem[0][0][0])[zi] = make_float4(0.f, 0.f, 0.f, 0.f);
    }
    __syncthreads();

    // ---- weights in VGPRs (R0/R8-proven form) ----
    float wreg[KK];
#pragma unroll
    for (int i = 0; i < KK; ++i) wreg[i] = wk_s[i];
    const float bv = bias[c];

    const int c4 = t & 31;                           // 4-col group
    const int strip = t >> 5;                        // 0..7
    const int sbase = strip * RPT;

    // ---- tile loop: prefetch next tile's DMA, compute current ----
#pragma unroll 1
    for (int tile = 0; tile < NTILE; ++tile) {
        const int cur = tile & 1;
        if (tile + 1 < NTILE) stage(tile + 1, cur ^ 1);  // streams during compute

        float* outp = out + (size_t)bc * HH * WW +
                      (size_t)(tile * TILE_H + sbase) * WW + c4 * 4;
        float acc[RPT][4];
#pragma unroll
        for (int i = 0; i < RPT; ++i)
            acc[i][0] = acc[i][1] = acc[i][2] = acc[i][3] = 0.f;

#pragma unroll
        for (int ir = 0; ir < RPT + KS - 1; ++ir) {  // 10 input rows
            const float4* row4 = (const float4*)&smem[cur][sbase + ir][0];
            const float4 f1 = row4[c4];
            float4 f0 = make_float4(0.f, 0.f, 0.f, 0.f);
            float4 f2 = make_float4(0.f, 0.f, 0.f, 0.f);
            if (c4 > 0)  f0 = row4[c4 - 1];          // cols -4..-1 (zero at left edge)
            if (c4 < 31) f2 = row4[c4 + 1];          // cols +4..+7 (zero at right edge)
            const float v[12] = {f0.x, f0.y, f0.z, f0.w,
                                 f1.x, f1.y, f1.z, f1.w,
                                 f2.x, f2.y, f2.z, f2.w};
#pragma unroll
            for (int ky = 0; ky < KS; ++ky) {
                const int o = ir - ky;               // pending output row (compile-time)
                if (o >= 0 && o < RPT) {
                    float* a = acc[o];
#pragma unroll
                    for (int kx = 0; kx < KS; ++kx) {
                        const float wv = wreg[ky * KS + kx];
                        a[0] += wv * v[1 + kx];
                        a[1] += wv * v[2 + kx];
                        a[2] += wv * v[3 + kx];
                        a[3] += wv * v[4 + kx];
                    }
                }
            }
            if (ir >= KS - 1) {                      // output row ir-6 complete
                float* a = acc[ir - (KS - 1)];
                float4 o4 = make_float4(a[0] + bv, a[1] + bv, a[2] + bv, a[3] + bv);
                *((float4*)(outp + (size_t)(ir - (KS - 1)) * WW)) = o4;
            }
        }

        if (tile + 1 < NTILE) {
            __syncthreads();                         // all waves done reading smem[cur];
                                                     // next tile's DMA drained (vmcnt 0)
            if (tile + 1 == NTILE - 1) {             // tile3: zero bottom halo in buf1
                if (t < 96)
                    ((float4*)&smem[1][0][0])[(SROWS - PAD) * (WW / 4) + t] =
                        make_float4(0.f, 0.f, 0.f, 0.f);
                __syncthreads();
            }
        }
    }
}

extern "C" void kernel_launch(void* const* d_in, const int* in_sizes, int n_in,
                              void* d_out, int out_size, void* d_ws, size_t ws_size,
                              hipStream_t stream) {
    const float* x     = (const float*)d_in[0];
    const float* w1    = (const float*)d_in[1];
    const float* gamma = (const float*)d_in[2];
    const float* beta  = (const float*)d_in[3];
    const float* mean  = (const float*)d_in[4];
    const float* var   = (const float*)d_in[5];
    const float* w2    = (const float*)d_in[6];
    const float* b2    = (const float*)d_in[7];
    const float* bias  = (const float*)d_in[8];
    float* out = (float*)d_out;

    float* pooled = (float*)d_ws;                    // B*DIM floats (6 KB, proven size)

    pool_kernel<<<BATCH * DIM, 256, 0, stream>>>(x, pooled);
    dwconv_fused_kernel<<<BATCH * DIM, 256, 0, stream>>>(
        x, pooled, w1, gamma, beta, mean, var, w2, b2, bias, out);
}